// Round 5
// baseline (106.587 us; speedup 1.0000x reference)
//
#include <hip/hip_runtime.h>
#include <math.h>

// PVConv2d: out = exp0(relu(conv3x3(log0(x), W) + bias)), Poincare ball c=0.01.
// x: [4,32,256,256] f32, Wk: [9,32,32] f32 ([k][o][c]), bias: [32] f32.
// R4: split into two streaming kernels (kill the lock-step fused phase structure;
// R1-R3 all plateaued at ~40 us regardless of occupancy).
//   A: log0+transpose. NCHW float4 reads -> shfl norm -> u bf16 NHWC in d_ws.
//      Also converts W->bf16 (block 0). 50 MB traffic ~ 8-9 us.
//   B: conv via MFMA with A-frags loaded DIRECTLY from global u (NHWC 16B/lane
//      == the 16x16x32 A-operand layout; L2/L3-hot since A just wrote it).
//      Zero-pad via masked edge loads. One barrier only (v->LDS for exp0 norm).

#define TW 32
#define TH 8
#define CIN 32
#define COUT 32

typedef __attribute__((ext_vector_type(8))) short bf16x8;
typedef __attribute__((ext_vector_type(4))) float f32x4;

__device__ inline unsigned short f2bf(float f) {
    unsigned int u = __builtin_bit_cast(unsigned int, f);
    return (unsigned short)((u + 0x7FFFu + ((u >> 16) & 1u)) >> 16);   // RNE
}
__device__ inline unsigned int pk2(float a, float b) {
    return (unsigned int)f2bf(a) | ((unsigned int)f2bf(b) << 16);
}

// ---- Kernel A: u = log0(x) as bf16 NHWC [b][p][c]; W -> bf16 ----
__global__ __launch_bounds__(256) void log0_kernel(
    const float* __restrict__ x, const float* __restrict__ Wk,
    unsigned short* __restrict__ wsW, unsigned short* __restrict__ u)
{
    const int t = threadIdx.x;
    const int x0 = blockIdx.x * TW, y0 = blockIdx.y * TH, b = blockIdx.z;

    if (blockIdx.x == 0 && blockIdx.y == 0 && blockIdx.z == 0) {
        for (int e = t; e < 9 * 32 * 32; e += 256) wsW[e] = f2bf(Wk[e]);
    }

    // task: t = ((row*8 + j) << 2) | cq  (row 0..7, j 0..7 float4-slot, cq 0..3)
    const int cq = t & 3, j = (t >> 2) & 7, row = t >> 5;
    const int gy = y0 + row, gxb = x0 + 4 * j;

    const float* xp = x + (size_t)(b * CIN + cq * 8) * 65536 + gy * 256 + gxb;
    float vv[4][8];
    #pragma unroll
    for (int cc = 0; cc < 8; ++cc) {
        float4 f4 = *(const float4*)(xp + (size_t)cc * 65536);
        vv[0][cc] = f4.x; vv[1][cc] = f4.y; vv[2][cc] = f4.z; vv[3][cc] = f4.w;
    }

    const size_t ubase = ((size_t)b * 65536 + (size_t)gy * 256 + gxb) * 32 + cq * 8;
    #pragma unroll
    for (int i = 0; i < 4; ++i) {
        float ss = 0.f;
        #pragma unroll
        for (int cc = 0; cc < 8; ++cc) ss = fmaf(vv[i][cc], vv[i][cc], ss);
        ss += __shfl_xor(ss, 1);          // partners share (row,j), differ cq
        ss += __shfl_xor(ss, 2);
        float n = fmaxf(sqrtf(ss), 1e-7f);
        float z = fminf(0.1f * n, 1.f - 1e-6f);
        float at = 0.5f * __logf((1.f + z) / (1.f - z));   // artanh(z)
        float s = at / (0.1f * n);
        unsigned int pk[4];
        #pragma unroll
        for (int w = 0; w < 4; ++w)
            pk[w] = pk2(vv[i][2 * w] * s, vv[i][2 * w + 1] * s);
        *(uint4*)(u + ubase + (size_t)i * 32) = *(uint4*)pk;
    }
}

// ---- Kernel B: conv3x3 MFMA from global u + bias/relu/exp0 + NCHW store ----
__global__ __launch_bounds__(256) void conv_kernel(
    const unsigned short* __restrict__ u, const unsigned short* __restrict__ wsW,
    const float* __restrict__ bias, float* __restrict__ out)
{
    __shared__ __align__(16) float v[256 * 36];   // 36864 B

    const int t = threadIdx.x;
    const int x0 = blockIdx.x * TW, y0 = blockIdx.y * TH, b = blockIdx.z;
    const int wv = t >> 6, lane = t & 63, m = lane & 15, quad = lane >> 4;

    f32x4 acc[2][4];
    #pragma unroll
    for (int n = 0; n < 2; ++n)
        #pragma unroll
        for (int mt = 0; mt < 4; ++mt) acc[n][mt] = (f32x4)0.f;

    const size_t bb = (size_t)b * 65536;
    #pragma unroll
    for (int tap = 0; tap < 9; ++tap) {
        const int dy = tap / 3, dx = tap - 3 * dy;
        const unsigned short* wrow = wsW + (tap * 32 + m) * 32 + quad * 8;
        bf16x8 B0 = *(const bf16x8*)wrow;
        bf16x8 B1 = *(const bf16x8*)(wrow + 512);   // o + 16
        #pragma unroll
        for (int mt = 0; mt < 4; ++mt) {
            const int pb = wv * 64 + mt * 16;
            const int gy = y0 + (pb >> 5) + dy - 1;
            const int gx = x0 + (pb & 31) + m + dx - 1;
            bf16x8 A;
            #pragma unroll
            for (int e = 0; e < 8; ++e) A[e] = 0;
            if ((unsigned)gy < 256u && (unsigned)gx < 256u)
                A = *(const bf16x8*)(u + (bb + (size_t)gy * 256 + gx) * 32 + quad * 8);
            acc[0][mt] = __builtin_amdgcn_mfma_f32_16x16x32_bf16(A, B0, acc[0][mt], 0, 0, 0);
            acc[1][mt] = __builtin_amdgcn_mfma_f32_16x16x32_bf16(A, B1, acc[1][mt], 0, 0, 0);
        }
    }

    // bias+relu, scatter v (f32, stride 36)
    // D layout: col = lane&15 -> channel, row = quad*4+r -> pixel offset
    const float bia0 = bias[m], bia1 = bias[16 + m];
    #pragma unroll
    for (int n = 0; n < 2; ++n)
        #pragma unroll
        for (int mt = 0; mt < 4; ++mt)
            #pragma unroll
            for (int r = 0; r < 4; ++r) {
                int pix = wv * 64 + mt * 16 + quad * 4 + r;
                float val = acc[n][mt][r] + (n ? bia1 : bia0);
                v[pix * 36 + n * 16 + m] = fmaxf(val, 0.f);
            }
    __syncthreads();

    // exp0 + coalesced NCHW store: thread t -> tile pixel t
    {
        float q[COUT];
        const float4* vp = (const float4*)&v[t * 36];
        #pragma unroll
        for (int jj = 0; jj < 8; ++jj) {
            float4 c4 = vp[jj];
            q[4 * jj] = c4.x; q[4 * jj + 1] = c4.y; q[4 * jj + 2] = c4.z; q[4 * jj + 3] = c4.w;
        }
        float ss = 0.f;
        #pragma unroll
        for (int o = 0; o < COUT; ++o) ss = fmaf(q[o], q[o], ss);
        float n = fmaxf(sqrtf(ss), 1e-7f);
        float a = 0.1f * n;
        float e = __expf(-2.f * a);
        float s = (1.f - e) / ((1.f + e) * a);   // tanh(a)/a
        const int px = t & 31, py = t >> 5;
        const size_t base = (size_t)b * COUT * 65536 + (size_t)(y0 + py) * 256 + (x0 + px);
        #pragma unroll
        for (int o = 0; o < COUT; ++o)
            out[base + (size_t)o * 65536] = s * q[o];
    }
}

extern "C" void kernel_launch(void* const* d_in, const int* in_sizes, int n_in,
                              void* d_out, int out_size, void* d_ws, size_t ws_size,
                              hipStream_t stream) {
    const float* x    = (const float*)d_in[0];
    const float* Wk   = (const float*)d_in[1];
    const float* bias = (const float*)d_in[2];
    float* out = (float*)d_out;

    unsigned short* wsW = (unsigned short*)d_ws;                     // 2304 B
    unsigned short* u   = (unsigned short*)((char*)d_ws + 32768);    // 16.78 MB

    dim3 grid(256 / TW, 256 / TH, 4);   // 8 x 32 x 4 = 1024 blocks
    log0_kernel<<<grid, dim3(256), 0, stream>>>(x, Wk, wsW, u);
    conv_kernel<<<grid, dim3(256), 0, stream>>>(u, wsW, bias, out);
}

// Round 6
// 99.731 us; speedup vs baseline: 1.0687x; 1.0687x over previous
//
#include <hip/hip_runtime.h>
#include <math.h>

// PVConv2d: out = exp0(relu(conv3x3(log0(x), W) + bias)), Poincare ball c=0.01.
// x: [4,32,256,256] f32, Wk: [9,32,32] f32 ([k][o][c]), bias: [32] f32.
// R5: R2 structure + intra-block row pipeline (producer/consumer wave split).
//   Wave w -> out rows 2w..2w+1. Phase A: all stage halo rows 0-5. Phase B:
//   waves 2,3 stage rows 6-9 (HBM) WHILE waves 0,1 MFMA (their rows need only
//   0-5). Phase C: waves 2,3 MFMA. 3 barriers total (same as R2), but staging
//   of 40% of the halo is hidden under MFMA.
//   LDS: u 340x64B swizzled (21760) + v bf16 [32][258] (16512) = 38.3 KB
//   -> 4 blocks/CU, u/v disjoint (no alias barrier). W: bf16 in d_ws via
//   wprep pre-kernel; B-frags = L2-hot global b128. Out stores non-temporal.

#define TW 32
#define TH 8
#define HW_ 34
#define NPIX 340
#define CIN 32
#define COUT 32
#define VSTR 258

typedef __attribute__((ext_vector_type(8))) short bf16x8;
typedef __attribute__((ext_vector_type(4))) float f32x4;

__device__ inline unsigned short f2bf(float f) {
    unsigned int u = __builtin_bit_cast(unsigned int, f);
    return (unsigned short)((u + 0x7FFFu + ((u >> 16) & 1u)) >> 16);   // RNE
}
__device__ inline unsigned int pk2(float a, float b) {
    return (unsigned int)f2bf(a) | ((unsigned int)f2bf(b) << 16);
}

__global__ __launch_bounds__(256) void wprep_kernel(
    const float* __restrict__ Wk, unsigned short* __restrict__ wsW)
{
    int i = blockIdx.x * 256 + threadIdx.x;
    if (i < 9 * 32 * 32) wsW[i] = f2bf(Wk[i]);
}

// stage one halo pixel p (global f32 NCHW -> log0 -> bf16 swizzled frags in u)
__device__ inline void stage_pixel(int p, int x0, int y0, int b,
                                   const float* __restrict__ x,
                                   unsigned char* __restrict__ u8)
{
    int py = p / HW_, px = p - py * HW_;
    int gy = y0 - 1 + py, gx = x0 - 1 + px;
    float vv[CIN];
    if ((unsigned)gy < 256u && (unsigned)gx < 256u) {
        const float* xp = x + (size_t)b * CIN * 65536 + gy * 256 + gx;
        #pragma unroll
        for (int c = 0; c < CIN; ++c) vv[c] = xp[(size_t)c * 65536];
    } else {
        #pragma unroll
        for (int c = 0; c < CIN; ++c) vv[c] = 0.f;
    }
    float ss = 0.f;
    #pragma unroll
    for (int c = 0; c < CIN; ++c) ss = fmaf(vv[c], vv[c], ss);
    float n = fmaxf(sqrtf(ss), 1e-7f);
    float z = fminf(0.1f * n, 1.f - 1e-6f);
    float at = 0.5f * __logf((1.f + z) / (1.f - z));   // artanh(z)
    float s = at / (0.1f * n);
    int swb = (p >> 1) & 3;
    uint4* row = (uint4*)(u8 + p * 64);
    #pragma unroll
    for (int j = 0; j < 4; ++j) {
        unsigned int pk[4];
        #pragma unroll
        for (int w = 0; w < 4; ++w)
            pk[w] = pk2(vv[j * 8 + 2 * w] * s, vv[j * 8 + 2 * w + 1] * s);
        row[j ^ swb] = *(uint4*)pk;
    }
}

__global__ __launch_bounds__(256, 4) void pvconv_kernel(
    const float* __restrict__ x, const unsigned short* __restrict__ wsW,
    const float* __restrict__ bias, float* __restrict__ out)
{
    __shared__ __align__(16) unsigned char smem[21760 + COUT * VSTR * 2];  // 38272 B
    unsigned char*  u8 = smem;                              // bf16 u, swizzled
    unsigned short* v  = (unsigned short*)(smem + 21760);   // bf16 v [ch][VSTR]

    const int t  = threadIdx.x;
    const int x0 = blockIdx.x * TW, y0 = blockIdx.y * TH, b = blockIdx.z;
    const int wv = t >> 6, lane = t & 63, m = lane & 15, quad = lane >> 4;

    // ---- Phase A: all threads stage halo rows 0-5 (px 0..203) ----
    if (t < 204) stage_pixel(t, x0, y0, b, x, u8);
    __syncthreads();   // s1

    // MFMA body for this wave (reads u rows 2wv..2wv+3, global W, writes v)
    auto do_mfma = [&]() {
        f32x4 acc[2][4];
        #pragma unroll
        for (int n = 0; n < 2; ++n)
            #pragma unroll
            for (int mt = 0; mt < 4; ++mt) acc[n][mt] = (f32x4)0.f;

        int apix[4];
        #pragma unroll
        for (int mt = 0; mt < 4; ++mt) {
            int pb = wv * 64 + mt * 16;
            apix[mt] = (pb >> 5) * HW_ + (pb & 31) + m;
        }
        #pragma unroll
        for (int tap = 0; tap < 9; ++tap) {
            const int dy = tap / 3, dx = tap - 3 * dy;
            const int hoff = dy * HW_ + dx;
            const unsigned short* wrow = wsW + (tap * 32 + m) * 32 + quad * 8;
            bf16x8 B0 = *(const bf16x8*)wrow;
            bf16x8 B1 = *(const bf16x8*)(wrow + 512);   // o + 16
            #pragma unroll
            for (int mt = 0; mt < 4; ++mt) {
                int hp = apix[mt] + hoff;
                bf16x8 A = *(const bf16x8*)(u8 + hp * 64 + ((quad ^ ((hp >> 1) & 3)) << 4));
                acc[0][mt] = __builtin_amdgcn_mfma_f32_16x16x32_bf16(A, B0, acc[0][mt], 0, 0, 0);
                acc[1][mt] = __builtin_amdgcn_mfma_f32_16x16x32_bf16(A, B1, acc[1][mt], 0, 0, 0);
            }
        }
        // bias+relu -> v bf16 [ch][px]  (ch = n*16+m, px = wv*64+mt*16+quad*4+r)
        const float bia0 = bias[m], bia1 = bias[16 + m];
        #pragma unroll
        for (int n = 0; n < 2; ++n)
            #pragma unroll
            for (int mt = 0; mt < 4; ++mt)
                #pragma unroll
                for (int r = 0; r < 4; ++r) {
                    int pix = wv * 64 + mt * 16 + quad * 4 + r;
                    float val = acc[n][mt][r] + (n ? bia1 : bia0);
                    v[(n * 16 + m) * VSTR + pix] = f2bf(fmaxf(val, 0.f));
                }
    };

    // ---- Phase B: waves 0,1 compute; waves 2,3 stage halo rows 6-9 ----
    if (wv < 2) {
        do_mfma();
    } else {
        int t2 = t - 128;                      // 0..127
        stage_pixel(204 + t2, x0, y0, b, x, u8);
        if (t2 < 8) stage_pixel(332 + t2, x0, y0, b, x, u8);
    }
    __syncthreads();   // s2: G1 u-writes visible to waves 2,3

    // ---- Phase C: waves 2,3 compute ----
    if (wv >= 2) do_mfma();
    __syncthreads();   // s3: all v visible

    // ---- exp0 + coalesced nt NCHW store: thread t -> tile pixel t ----
    {
        float q[COUT];
        float ss = 0.f;
        #pragma unroll
        for (int o = 0; o < COUT; ++o) {
            unsigned int w16 = v[o * VSTR + t];
            q[o] = __builtin_bit_cast(float, w16 << 16);
            ss = fmaf(q[o], q[o], ss);
        }
        float n = fmaxf(sqrtf(ss), 1e-7f);
        float a = 0.1f * n;
        float e = __expf(-2.f * a);
        float s = (1.f - e) / ((1.f + e) * a);   // tanh(a)/a
        const int px = t & 31, py = t >> 5;
        const size_t base = (size_t)b * COUT * 65536 + (size_t)(y0 + py) * 256 + (x0 + px);
        #pragma unroll
        for (int o = 0; o < COUT; ++o)
            __builtin_nontemporal_store(s * q[o], &out[base + (size_t)o * 65536]);
    }
}

extern "C" void kernel_launch(void* const* d_in, const int* in_sizes, int n_in,
                              void* d_out, int out_size, void* d_ws, size_t ws_size,
                              hipStream_t stream) {
    const float* x    = (const float*)d_in[0];
    const float* Wk   = (const float*)d_in[1];
    const float* bias = (const float*)d_in[2];
    float* out = (float*)d_out;
    unsigned short* wsW = (unsigned short*)d_ws;   // 9*32*32 bf16 = 18432 B

    wprep_kernel<<<dim3(36), dim3(256), 0, stream>>>(Wk, wsW);
    dim3 grid(256 / TW, 256 / TH, 4);              // 8 x 32 x 4 = 1024 blocks
    pvconv_kernel<<<grid, dim3(256), 0, stream>>>(x, wsW, bias, out);
}